// Round 1
// 69.997 us; speedup vs baseline: 1.1811x; 1.1811x over previous
//
#include <hip/hip_runtime.h>
#include <math.h>

#define NBOX 16
#define GX 64
#define GY 64
#define GZ 8
#define NVOX (GX * GY * GZ)             // 32768
#define BLK 256                         // 4 waves per block
#define WAVES 4
#define BOXES_PER_WAVE (NBOX / WAVES)   // 4
#define BLOCKS_PER_BATCH (NVOX / 64)    // 512 blocks, 64 voxels each

// ---------------------------------------------------------------------------
// Fully scalar (no arrays -> no alloca -> no scratch) Sutherland-Hodgman clip.
// Vertex buffers are named registers i0x..i7y (input) / q0x..q7y (output).
// The dynamic append becomes an explicit v_cndmask select chain over slots,
// truncated to the provable per-stage max vertex count (5/6/7/8).
// Emission order per edge (intersection point, then next-vertex) matches the
// reference's stable argsort compaction bit-exactly.
// ---------------------------------------------------------------------------

#define EMIT_SLOT(K, PX, PY) \
    q##K##x = (_c && oc == K) ? (PX) : q##K##x; \
    q##K##y = (_c && oc == K) ? (PY) : q##K##y;

// NSL = compile-time max output-vertex count for this stage; slots >= NSL are
// provably never written (convex n-gon vs half-plane emits <= n+1 verts).
#define EMITC(NSL, COND, PX, PY) do { const bool _c = (COND); \
    EMIT_SLOT(0, PX, PY) EMIT_SLOT(1, PX, PY) EMIT_SLOT(2, PX, PY) \
    EMIT_SLOT(3, PX, PY) \
    if ((NSL) > 4) { EMIT_SLOT(4, PX, PY) } \
    if ((NSL) > 5) { EMIT_SLOT(5, PX, PY) } \
    if ((NSL) > 6) { EMIT_SLOT(6, PX, PY) } \
    if ((NSL) > 7) { EMIT_SLOT(7, PX, PY) } \
    oc += _c ? 1 : 0; } while (0)

// One SH edge step: cur = vertex E, next = (E+1<cnt) ? vertex NE : vertex 0.
// All garbage values (E >= cnt) are gated out by _cv before emission.
#define CLIP_EDGE(E, NE, NSL) do { \
    const bool  _cv = (E) < cnt; \
    const bool  _wr = !((E) + 1 < cnt); \
    const float _cx = i##E##x, _cy = i##E##y; \
    const float _nx = _wr ? i0x : i##NE##x; \
    const float _ny = _wr ? i0y : i##NE##y; \
    const float _dc = pa * _cx + pb * _cy + pc; \
    const float _dn = pa * _nx + pb * _ny + pc; \
    float _dm = _dc - _dn; \
    _dm = (fabsf(_dm) < 1e-12f) ? 1.0f : _dm; \
    const float _tt  = _dc / _dm; \
    const float _ipx = _cx + _tt * (_nx - _cx); \
    const float _ipy = _cy + _tt * (_ny - _cy); \
    { const bool _e1 = _cv && ((_dc >= 0.0f) != (_dn >= 0.0f)); EMITC(NSL, _e1, _ipx, _ipy); } \
    { const bool _e2 = _cv && (_dn >= 0.0f);                    EMITC(NSL, _e2, _nx, _ny); } \
} while (0)

#define STAGE_DECL_Q() \
    float q0x = 0.0f, q0y = 0.0f, q1x = 0.0f, q1y = 0.0f, \
          q2x = 0.0f, q2y = 0.0f, q3x = 0.0f, q3y = 0.0f, \
          q4x = 0.0f, q4y = 0.0f, q5x = 0.0f, q5y = 0.0f, \
          q6x = 0.0f, q6y = 0.0f, q7x = 0.0f, q7y = 0.0f; \
    int oc = 0;

#define COPY_Q_TO_I() \
    i0x = q0x; i0y = q0y; i1x = q1x; i1y = q1y; \
    i2x = q2x; i2y = q2y; i3x = q3x; i3y = q3y; \
    i4x = q4x; i4y = q4y; i5x = q5x; i5y = q5y; \
    i6x = q6x; i6y = q6y; i7x = q7x; i7y = q7y; \
    cnt = oc;

#define SHOE(E, NE) { \
    const bool  _v  = (E) < cnt; \
    const bool  _wr = !((E) + 1 < cnt); \
    const float _nx = _wr ? i0x : i##NE##x; \
    const float _ny = _wr ? i0y : i##NE##y; \
    const float _cr = i##E##x * _ny - _nx * i##E##y; \
    ssum += _v ? _cr : 0.0f; }

// Block = 256 threads = 4 waves, all covering the SAME 64-voxel tile.
// Wave w handles boxes [4w, 4w+4); LDS argmax reduction afterward preserves
// jnp.argmax first-max semantics (box index is monotone in wave index, and
// both the per-wave loop and the cross-wave combine use strict >).
__global__ __launch_bounds__(BLK, 4) void box3d_encoder_kernel(
    const float* __restrict__ corners,   // (B, 16, 8, 3)
    const float* __restrict__ vsizes,    // (B, 3) -- reference uses row 0 only
    float* __restrict__ out)             // (B*NVOX, 2)
{
    __shared__ float s_px[NBOX][4], s_py[NBOX][4];
    __shared__ float s_zb0[NBOX], s_zb1[NBOX], s_qa[NBOX];
    __shared__ float s_sin[NBOX], s_cos[NBOX];
    __shared__ float s_ax0[NBOX], s_ax1[NBOX], s_ay0[NBOX], s_ay1[NBOX];
    __shared__ float s_biou[WAVES][64];
    __shared__ float s_bint[WAVES][64];
    __shared__ int   s_bidx[WAVES][64];

    const int b     = blockIdx.x >> 9;              // / BLOCKS_PER_BATCH
    const int vbase = (blockIdx.x & (BLOCKS_PER_BATCH - 1)) << 6;
    const int t     = threadIdx.x;
    const int w     = t >> 6;                       // wave id 0..3
    const int lane  = t & 63;                       // voxel lane within tile

    const float vs0 = vsizes[0], vs1 = vsizes[1], vs2 = vsizes[2];
    const float vox_vol = vs0 * vs1 * vs2;

    if (t < NBOX) {
        const float* c8 = corners + ((size_t)b * NBOX + t) * 8 * 3;
        float px[4], py[4];
        float zmin = c8[2], zmax = c8[2];
        #pragma unroll
        for (int k = 0; k < 8; k++) {
            float z = c8[k * 3 + 2];
            zmin = fminf(zmin, z);
            zmax = fmaxf(zmax, z);
        }
        #pragma unroll
        for (int k = 0; k < 4; k++) { px[k] = c8[k * 3 + 0]; py[k] = c8[k * 3 + 1]; }

        float sum = 0.0f;
        #pragma unroll
        for (int k = 0; k < 4; k++) {
            int n = (k + 1) & 3;
            sum += px[k] * py[n] - px[n] * py[k];
        }
        s_qa[t] = 0.5f * fabsf(sum);

        float h = atan2f(py[0] - py[3], px[0] - px[3]);
        s_sin[t] = sinf(h);
        s_cos[t] = cosf(h);

        s_zb0[t] = zmin;
        s_zb1[t] = zmax;

        float ax0 = px[0], ax1 = px[0], ay0 = py[0], ay1 = py[0];
        #pragma unroll
        for (int k = 1; k < 4; k++) {
            ax0 = fminf(ax0, px[k]); ax1 = fmaxf(ax1, px[k]);
            ay0 = fminf(ay0, py[k]); ay1 = fmaxf(ay1, py[k]);
        }
        s_ax0[t] = ax0; s_ax1[t] = ax1; s_ay0[t] = ay0; s_ay1[t] = ay1;

        #pragma unroll
        for (int k = 0; k < 4; k++) { s_px[t][k] = px[k]; s_py[t][k] = py[k]; }
    }
    __syncthreads();

    // voxel indices: v = i*512 + j*8 + k ; tile covers 8j x 8k, single i
    const int v  = vbase + lane;
    const int iz = v & 7;
    const int iy = (v >> 3) & 63;
    const int ix = v >> 9;
    const float fi = (float)(ix - 32);
    const float fj = (float)(iy - 32);
    const float fk = (float)(iz - 4);
    const float x0 = fi * vs0, x1 = (fi + 1.0f) * vs0;
    const float y0 = fj * vs1, y1 = (fj + 1.0f) * vs1;
    const float z0 = fk * vs2, z1 = (fk + 1.0f) * vs2;

    float best_iou   = -1.0f;
    float best_inter = 0.0f;
    int   best_idx   = 0;

    #pragma unroll 1
    for (int nn = 0; nn < BOXES_PER_WAVE; nn++) {
        const int n = (w << 2) + nn;
        float iou = 0.0f, inter = 0.0f;

        const float zb0 = s_zb0[n], zb1 = s_zb1[n];
        const float zov_raw = fminf(z1, zb1) - fmaxf(z0, zb0);
        const bool overlap = (zov_raw > 0.0f)
                          && (s_ax0[n] < x1) && (s_ax1[n] > x0)
                          && (s_ay0[n] < y1) && (s_ay1[n] > y0);

        // Wave-uniform gate: whole wave skips when no lane overlaps box n.
        // Inside, all lanes compute the full reference formula (clip area is
        // exactly 0 and zov clamps to 0 for non-overlapping lanes).
        if (__any((int)overlap)) {
            float i0x = s_px[n][0], i0y = s_py[n][0];
            float i1x = s_px[n][1], i1y = s_py[n][1];
            float i2x = s_px[n][2], i2y = s_py[n][2];
            float i3x = s_px[n][3], i3y = s_py[n][3];
            float i4x = 0.0f, i4y = 0.0f, i5x = 0.0f, i5y = 0.0f;
            float i6x = 0.0f, i6y = 0.0f, i7x = 0.0f, i7y = 0.0f;
            int cnt = 4;

            {   // plane x >= x0 : 4 -> <=5
                const float pa = 1.0f, pb = 0.0f, pc = -x0;
                STAGE_DECL_Q();
                CLIP_EDGE(0, 1, 5); CLIP_EDGE(1, 2, 5); CLIP_EDGE(2, 3, 5);
                CLIP_EDGE(3, 4, 5);
                COPY_Q_TO_I();
            }
            {   // plane x <= x1 : <=5 -> <=6
                const float pa = -1.0f, pb = 0.0f, pc = x1;
                STAGE_DECL_Q();
                CLIP_EDGE(0, 1, 6); CLIP_EDGE(1, 2, 6); CLIP_EDGE(2, 3, 6);
                CLIP_EDGE(3, 4, 6); CLIP_EDGE(4, 5, 6);
                COPY_Q_TO_I();
            }
            {   // plane y >= y0 : <=6 -> <=7
                const float pa = 0.0f, pb = 1.0f, pc = -y0;
                STAGE_DECL_Q();
                CLIP_EDGE(0, 1, 7); CLIP_EDGE(1, 2, 7); CLIP_EDGE(2, 3, 7);
                CLIP_EDGE(3, 4, 7); CLIP_EDGE(4, 5, 7); CLIP_EDGE(5, 6, 7);
                COPY_Q_TO_I();
            }
            {   // plane y <= y1 : <=7 -> <=8
                const float pa = 0.0f, pb = -1.0f, pc = y1;
                STAGE_DECL_Q();
                CLIP_EDGE(0, 1, 8); CLIP_EDGE(1, 2, 8); CLIP_EDGE(2, 3, 8);
                CLIP_EDGE(3, 4, 8); CLIP_EDGE(4, 5, 8); CLIP_EDGE(5, 6, 8);
                CLIP_EDGE(6, 7, 8);
                COPY_Q_TO_I();
            }

            float ssum = 0.0f;
            SHOE(0, 1) SHOE(1, 2) SHOE(2, 3) SHOE(3, 4)
            SHOE(4, 5) SHOE(5, 6) SHOE(6, 7) SHOE(7, 7)
            const float area = 0.5f * fabsf(ssum);

            const float zov = fmaxf(zov_raw, 0.0f);
            inter = area * zov;
            const float box_vol = s_qa[n] * (zb1 - zb0);
            iou = inter / (vox_vol + box_vol - inter + 1e-9f);
        }

        if (iou > best_iou) {   // strict > => first-max within this wave's boxes
            best_iou   = iou;
            best_inter = inter;
            best_idx   = n;
        }
    }

    s_biou[w][lane] = best_iou;
    s_bint[w][lane] = best_inter;
    s_bidx[w][lane] = best_idx;
    __syncthreads();

    // Wave 0 combines the 4 partials in increasing wave (= box-index) order
    // with strict > : exact first-max over all 16 boxes, matching jnp.argmax.
    if (w == 0) {
        float fiou = s_biou[0][lane];
        float fint = s_bint[0][lane];
        int   fidx = s_bidx[0][lane];
        #pragma unroll
        for (int ww = 1; ww < WAVES; ww++) {
            const float iou2 = s_biou[ww][lane];
            if (iou2 > fiou) {
                fiou = iou2;
                fint = s_bint[ww][lane];
                fidx = s_bidx[ww][lane];
            }
        }
        const bool mask = fint > 0.5f * vox_vol;
        float2 o;
        o.x = mask ? s_sin[fidx] : 0.0f;
        o.y = mask ? s_cos[fidx] : 0.0f;
        reinterpret_cast<float2*>(out)[(size_t)b * NVOX + v] = o;
    }
}

extern "C" void kernel_launch(void* const* d_in, const int* in_sizes, int n_in,
                              void* d_out, int out_size, void* d_ws, size_t ws_size,
                              hipStream_t stream) {
    const float* corners = (const float*)d_in[0];   // (4,16,8,3) fp32
    const float* vsizes  = (const float*)d_in[1];   // (4,3) fp32
    float* out = (float*)d_out;                     // (4*32768, 2) fp32

    const int B = 4;
    dim3 grid(B * BLOCKS_PER_BATCH);  // 2048 blocks of 4 waves = 8192 waves
    dim3 block(BLK);                  // 256 threads
    box3d_encoder_kernel<<<grid, block, 0, stream>>>(corners, vsizes, out);
}

// Round 2
// 63.135 us; speedup vs baseline: 1.3094x; 1.1087x over previous
//
#include <hip/hip_runtime.h>
#include <math.h>

#define NBOX 16
#define GX 64
#define GY 64
#define GZ 8
#define NVOX (GX * GY * GZ)             // 32768
#define BLK 1024                        // 16 waves: wave w owns box w
#define TILES 64                        // 8x8 XY tiles of 8x8 cells per batch

// ---------------------------------------------------------------------------
// Fully scalar (no arrays -> no alloca -> no scratch) Sutherland-Hodgman clip.
// Vertex buffers are named registers i0x..i7y (input) / q0x..q7y (output).
// The dynamic append becomes an explicit v_cndmask select chain over slots,
// truncated to the provable per-stage max vertex count (5/6/7/8).
// Emission order per edge (intersection point, then next-vertex) matches the
// reference's stable argsort compaction bit-exactly.
// ---------------------------------------------------------------------------

#define EMIT_SLOT(K, PX, PY) \
    q##K##x = (_c && oc == K) ? (PX) : q##K##x; \
    q##K##y = (_c && oc == K) ? (PY) : q##K##y;

// NSL = compile-time max output-vertex count for this stage; slots >= NSL are
// provably never written (convex n-gon vs half-plane emits <= n+1 verts).
#define EMITC(NSL, COND, PX, PY) do { const bool _c = (COND); \
    EMIT_SLOT(0, PX, PY) EMIT_SLOT(1, PX, PY) EMIT_SLOT(2, PX, PY) \
    EMIT_SLOT(3, PX, PY) \
    if ((NSL) > 4) { EMIT_SLOT(4, PX, PY) } \
    if ((NSL) > 5) { EMIT_SLOT(5, PX, PY) } \
    if ((NSL) > 6) { EMIT_SLOT(6, PX, PY) } \
    if ((NSL) > 7) { EMIT_SLOT(7, PX, PY) } \
    oc += _c ? 1 : 0; } while (0)

// One SH edge step: cur = vertex E, next = (E+1<cnt) ? vertex NE : vertex 0.
// All garbage values (E >= cnt) are gated out by _cv before emission.
#define CLIP_EDGE(E, NE, NSL) do { \
    const bool  _cv = (E) < cnt; \
    const bool  _wr = !((E) + 1 < cnt); \
    const float _cx = i##E##x, _cy = i##E##y; \
    const float _nx = _wr ? i0x : i##NE##x; \
    const float _ny = _wr ? i0y : i##NE##y; \
    const float _dc = pa * _cx + pb * _cy + pc; \
    const float _dn = pa * _nx + pb * _ny + pc; \
    float _dm = _dc - _dn; \
    _dm = (fabsf(_dm) < 1e-12f) ? 1.0f : _dm; \
    const float _tt  = _dc / _dm; \
    const float _ipx = _cx + _tt * (_nx - _cx); \
    const float _ipy = _cy + _tt * (_ny - _cy); \
    { const bool _e1 = _cv && ((_dc >= 0.0f) != (_dn >= 0.0f)); EMITC(NSL, _e1, _ipx, _ipy); } \
    { const bool _e2 = _cv && (_dn >= 0.0f);                    EMITC(NSL, _e2, _nx, _ny); } \
} while (0)

#define STAGE_DECL_Q() \
    float q0x = 0.0f, q0y = 0.0f, q1x = 0.0f, q1y = 0.0f, \
          q2x = 0.0f, q2y = 0.0f, q3x = 0.0f, q3y = 0.0f, \
          q4x = 0.0f, q4y = 0.0f, q5x = 0.0f, q5y = 0.0f, \
          q6x = 0.0f, q6y = 0.0f, q7x = 0.0f, q7y = 0.0f; \
    int oc = 0;

#define COPY_Q_TO_I() \
    i0x = q0x; i0y = q0y; i1x = q1x; i1y = q1y; \
    i2x = q2x; i2y = q2y; i3x = q3x; i3y = q3y; \
    i4x = q4x; i4y = q4y; i5x = q5x; i5y = q5y; \
    i6x = q6x; i6y = q6y; i7x = q7x; i7y = q7y; \
    cnt = oc;

#define SHOE(E, NE) { \
    const bool  _v  = (E) < cnt; \
    const bool  _wr = !((E) + 1 < cnt); \
    const float _nx = _wr ? i0x : i##NE##x; \
    const float _ny = _wr ? i0y : i##NE##y; \
    const float _cr = i##E##x * _ny - _nx * i##E##y; \
    ssum += _v ? _cr : 0.0f; }

// Block = 1024 threads = 16 waves, covering one 8x8 XY patch (all 8 z layers
// = 512 voxels). Wave w handles box w exclusively: the SH clip area depends
// only on (x,y), so it is computed ONCE per XY cell and reused across the 8
// z layers via a register loop (bit-exact: reference does identical FP ops
// for every z of a column). LDS argmax over n=0..15 ascending with strict >
// preserves jnp.argmax first-max semantics exactly.
__global__ __launch_bounds__(BLK, 4) void box3d_encoder_kernel(
    const float* __restrict__ corners,   // (B, 16, 8, 3)
    const float* __restrict__ vsizes,    // (B, 3) -- reference uses row 0 only
    float* __restrict__ out)             // (B*NVOX, 2)
{
    __shared__ float s_px[NBOX][4], s_py[NBOX][4];
    __shared__ float s_zb0[NBOX], s_zb1[NBOX], s_qa[NBOX];
    __shared__ float s_sin[NBOX], s_cos[NBOX];
    __shared__ float s_ax0[NBOX], s_ax1[NBOX], s_ay0[NBOX], s_ay1[NBOX];
    __shared__ float s_iou[NBOX][64][8];   // [box][xy][z]
    __shared__ float s_int[NBOX][64][8];

    const int b    = blockIdx.x >> 6;      // / TILES
    const int tile = blockIdx.x & 63;
    const int tix  = tile >> 3;            // tile x (0..7)
    const int tiy  = tile & 7;             // tile y (0..7)
    const int t    = threadIdx.x;
    const int w    = t >> 6;               // wave id == box id (0..15)
    const int lane = t & 63;               // XY cell within 8x8 patch

    const float vs0 = vsizes[0], vs1 = vsizes[1], vs2 = vsizes[2];
    const float vox_vol = vs0 * vs1 * vs2;

    if (t < NBOX) {
        const float* c8 = corners + ((size_t)b * NBOX + t) * 8 * 3;
        float px[4], py[4];
        float zmin = c8[2], zmax = c8[2];
        #pragma unroll
        for (int k = 0; k < 8; k++) {
            float z = c8[k * 3 + 2];
            zmin = fminf(zmin, z);
            zmax = fmaxf(zmax, z);
        }
        #pragma unroll
        for (int k = 0; k < 4; k++) { px[k] = c8[k * 3 + 0]; py[k] = c8[k * 3 + 1]; }

        float sum = 0.0f;
        #pragma unroll
        for (int k = 0; k < 4; k++) {
            int n = (k + 1) & 3;
            sum += px[k] * py[n] - px[n] * py[k];
        }
        s_qa[t] = 0.5f * fabsf(sum);

        float h = atan2f(py[0] - py[3], px[0] - px[3]);
        s_sin[t] = sinf(h);
        s_cos[t] = cosf(h);

        s_zb0[t] = zmin;
        s_zb1[t] = zmax;

        float ax0 = px[0], ax1 = px[0], ay0 = py[0], ay1 = py[0];
        #pragma unroll
        for (int k = 1; k < 4; k++) {
            ax0 = fminf(ax0, px[k]); ax1 = fmaxf(ax1, px[k]);
            ay0 = fminf(ay0, py[k]); ay1 = fmaxf(ay1, py[k]);
        }
        s_ax0[t] = ax0; s_ax1[t] = ax1; s_ay0[t] = ay0; s_ay1[t] = ay1;

        #pragma unroll
        for (int k = 0; k < 4; k++) { s_px[t][k] = px[k]; s_py[t][k] = py[k]; }
    }
    __syncthreads();

    // XY cell of this lane
    const int ixl = lane >> 3;             // 0..7 within tile
    const int iyl = lane & 7;
    const float fi = (float)(tix * 8 + ixl - 32);
    const float fj = (float)(tiy * 8 + iyl - 32);
    const float x0 = fi * vs0, x1 = (fi + 1.0f) * vs0;
    const float y0 = fj * vs1, y1 = (fj + 1.0f) * vs1;
    // whole-grid z range for the gate (iz 0..7 -> fk -4..3)
    const float zgl = -4.0f * vs2, zgh = 4.0f * vs2;

    float riou0 = 0.0f, riou1 = 0.0f, riou2 = 0.0f, riou3 = 0.0f,
          riou4 = 0.0f, riou5 = 0.0f, riou6 = 0.0f, riou7 = 0.0f;
    float rint0 = 0.0f, rint1 = 0.0f, rint2 = 0.0f, rint3 = 0.0f,
          rint4 = 0.0f, rint5 = 0.0f, rint6 = 0.0f, rint7 = 0.0f;

    const float zb0 = s_zb0[w], zb1 = s_zb1[w];
    const bool overlap = (fminf(zgh, zb1) > fmaxf(zgl, zb0))
                      && (s_ax0[w] < x1) && (s_ax1[w] > x0)
                      && (s_ay0[w] < y1) && (s_ay1[w] > y0);

    // Wave-uniform gate: whole wave skips when no lane's column can overlap
    // box w. Gated-out results are exact zeros, matching the reference
    // (area==0 when XY disjoint, zov clamps to 0 when z disjoint).
    if (__any((int)overlap)) {
        float i0x = s_px[w][0], i0y = s_py[w][0];
        float i1x = s_px[w][1], i1y = s_py[w][1];
        float i2x = s_px[w][2], i2y = s_py[w][2];
        float i3x = s_px[w][3], i3y = s_py[w][3];
        float i4x = 0.0f, i4y = 0.0f, i5x = 0.0f, i5y = 0.0f;
        float i6x = 0.0f, i6y = 0.0f, i7x = 0.0f, i7y = 0.0f;
        int cnt = 4;

        {   // plane x >= x0 : 4 -> <=5
            const float pa = 1.0f, pb = 0.0f, pc = -x0;
            STAGE_DECL_Q();
            CLIP_EDGE(0, 1, 5); CLIP_EDGE(1, 2, 5); CLIP_EDGE(2, 3, 5);
            CLIP_EDGE(3, 4, 5);
            COPY_Q_TO_I();
        }
        {   // plane x <= x1 : <=5 -> <=6
            const float pa = -1.0f, pb = 0.0f, pc = x1;
            STAGE_DECL_Q();
            CLIP_EDGE(0, 1, 6); CLIP_EDGE(1, 2, 6); CLIP_EDGE(2, 3, 6);
            CLIP_EDGE(3, 4, 6); CLIP_EDGE(4, 5, 6);
            COPY_Q_TO_I();
        }
        {   // plane y >= y0 : <=6 -> <=7
            const float pa = 0.0f, pb = 1.0f, pc = -y0;
            STAGE_DECL_Q();
            CLIP_EDGE(0, 1, 7); CLIP_EDGE(1, 2, 7); CLIP_EDGE(2, 3, 7);
            CLIP_EDGE(3, 4, 7); CLIP_EDGE(4, 5, 7); CLIP_EDGE(5, 6, 7);
            COPY_Q_TO_I();
        }
        {   // plane y <= y1 : <=7 -> <=8
            const float pa = 0.0f, pb = -1.0f, pc = y1;
            STAGE_DECL_Q();
            CLIP_EDGE(0, 1, 8); CLIP_EDGE(1, 2, 8); CLIP_EDGE(2, 3, 8);
            CLIP_EDGE(3, 4, 8); CLIP_EDGE(4, 5, 8); CLIP_EDGE(5, 6, 8);
            CLIP_EDGE(6, 7, 8);
            COPY_Q_TO_I();
        }

        float ssum = 0.0f;
        SHOE(0, 1) SHOE(1, 2) SHOE(2, 3) SHOE(3, 4)
        SHOE(4, 5) SHOE(5, 6) SHOE(6, 7) SHOE(7, 7)
        const float area = 0.5f * fabsf(ssum);

        const float box_vol = s_qa[w] * (zb1 - zb0);

        // z loop: area is z-invariant; replicate the reference per-z formula.
        #define ZSTEP(Z) { \
            const float fk  = (float)((Z) - 4); \
            const float zz0 = fk * vs2, zz1 = (fk + 1.0f) * vs2; \
            const float zov = fmaxf(fminf(zz1, zb1) - fmaxf(zz0, zb0), 0.0f); \
            const float inter = area * zov; \
            rint##Z = inter; \
            riou##Z = inter / (vox_vol + box_vol - inter + 1e-9f); }
        ZSTEP(0) ZSTEP(1) ZSTEP(2) ZSTEP(3)
        ZSTEP(4) ZSTEP(5) ZSTEP(6) ZSTEP(7)
        #undef ZSTEP
    }

    // publish per-(box, xy, z) results; 32B contiguous per lane -> 2x b128
    reinterpret_cast<float4*>(&s_iou[w][lane][0])[0] =
        make_float4(riou0, riou1, riou2, riou3);
    reinterpret_cast<float4*>(&s_iou[w][lane][4])[0] =
        make_float4(riou4, riou5, riou6, riou7);
    reinterpret_cast<float4*>(&s_int[w][lane][0])[0] =
        make_float4(rint0, rint1, rint2, rint3);
    reinterpret_cast<float4*>(&s_int[w][lane][4])[0] =
        make_float4(rint4, rint5, rint6, rint7);
    __syncthreads();

    // Reduction: one thread per voxel (512 of 1024 threads). Ascending n with
    // strict > == first-max over all 16 boxes, matching jnp.argmax exactly.
    if (t < 512) {
        const int xy = t >> 3;             // 0..63
        const int z  = t & 7;
        float fiou = s_iou[0][xy][z];
        float fint = s_int[0][xy][z];
        int   fidx = 0;
        #pragma unroll
        for (int n = 1; n < NBOX; n++) {
            const float i2 = s_iou[n][xy][z];
            const float t2 = s_int[n][xy][z];
            const bool  g  = i2 > fiou;
            fiou = g ? i2 : fiou;
            fint = g ? t2 : fint;
            fidx = g ? n  : fidx;
        }
        const bool mask = fint > 0.5f * vox_vol;
        float2 o;
        o.x = mask ? s_sin[fidx] : 0.0f;
        o.y = mask ? s_cos[fidx] : 0.0f;
        const int ix = tix * 8 + (xy >> 3);
        const int iy = tiy * 8 + (xy & 7);
        reinterpret_cast<float2*>(out)[(size_t)b * NVOX + ix * 512 + iy * 8 + z] = o;
    }
}

extern "C" void kernel_launch(void* const* d_in, const int* in_sizes, int n_in,
                              void* d_out, int out_size, void* d_ws, size_t ws_size,
                              hipStream_t stream) {
    const float* corners = (const float*)d_in[0];   // (4,16,8,3) fp32
    const float* vsizes  = (const float*)d_in[1];   // (4,3) fp32
    float* out = (float*)d_out;                     // (4*32768, 2) fp32

    const int B = 4;
    dim3 grid(B * TILES);             // 256 blocks of 16 waves = 4096 waves
    dim3 block(BLK);                  // 1024 threads
    box3d_encoder_kernel<<<grid, block, 0, stream>>>(corners, vsizes, out);
}